// Round 9
// baseline (355.497 us; speedup 1.0000x reference)
//
#include <hip/hip_runtime.h>
#include <hip/hip_bf16.h>

#define Bb   16
#define FIN  64
#define FOUT 128
#define NN   2048
#define KK   20
#define LCAP 32      // capture list size (approx top-32), refined to exact top-20
#define BUFD 112     // per-row LDS candidate buffer depth
#define TRIP 48      // set flush flag when cnt exceeds this (flush BEFORE next compact)

typedef unsigned long long u64;
typedef __attribute__((ext_vector_type(8))) __bf16 bf16x8;
typedef __attribute__((ext_vector_type(4))) float  f32x4;

static __device__ __forceinline__ unsigned short f2bf(float f) {
  unsigned u = __float_as_uint(f);
  unsigned r = (u + 0x7fff + ((u >> 16) & 1)) >> 16;   // RNE
  return (unsigned short)r;
}
static __device__ __forceinline__ float bf2f(unsigned short b) {
  return __uint_as_float(((unsigned)b) << 16);
}
static __device__ __forceinline__ void gll16(const void* g, void* l) {
  __builtin_amdgcn_global_load_lds(
      (const __attribute__((address_space(1))) unsigned int*)g,
      (__attribute__((address_space(3))) unsigned int*)l, 16, 0, 0);
}

// 4-row interleaved flush: sorts each row's candidate chunk (bitonic-64) and
// merges into that row's register-resident sorted top-32. The 4 rows'
// shuffle chains are independent -> ILP hides the DS latency.
static __device__ __forceinline__ void flush4(unsigned lst[4], int cnt[4], unsigned thr[4],
                                              const unsigned* bufw, int lane) {
  int mc = max(max(cnt[0], cnt[1]), max(cnt[2], cnt[3]));
  for (int base = 0; base < mc; base += 64) {
    unsigned c[4];
#pragma unroll
    for (int r = 0; r < 4; ++r)
      c[r] = (base + lane < cnt[r]) ? bufw[r * BUFD + base + lane] : 0xFFFFFFFFu;
    // interleaved bitonic sort-64 (ascending)
#pragma unroll
    for (int size = 2; size <= 64; size <<= 1) {
#pragma unroll
      for (int stride = size >> 1; stride; stride >>= 1) {
        bool dir = (((lane & size) == 0) == ((lane & stride) == 0));
#pragma unroll
        for (int r = 0; r < 4; ++r) {
          unsigned o = __shfl_xor(c[r], stride);
          bool lt = o < c[r];
          c[r] = dir ? (lt ? o : c[r]) : (lt ? c[r] : o);
        }
      }
    }
    // interleaved merge into sorted top-32
#pragma unroll
    for (int r = 0; r < 4; ++r) {
      unsigned rs = __shfl(c[r], 31 - (lane & 31));
      c[r] = lst[r] < rs ? lst[r] : rs;    // bitonic
    }
#pragma unroll
    for (int stride = 16; stride; stride >>= 1) {
#pragma unroll
      for (int r = 0; r < 4; ++r) {
        unsigned o = __shfl_xor(c[r], stride);
        unsigned mn = c[r] < o ? c[r] : o, mx = c[r] < o ? o : c[r];
        c[r] = ((lane & stride) == 0) ? mn : mx;
      }
    }
#pragma unroll
    for (int r = 0; r < 4; ++r)
      lst[r] = (lane >= 32) ? 0xFFFFFFFFu : c[r];
  }
#pragma unroll
  for (int r = 0; r < 4; ++r) { thr[r] = __shfl(lst[r], 31); cnt[r] = 0; }
}

// ---------------------------------------------------------------- prep
// transpose x -> xt32[b][n][f]; bf16 hi/lo MFMA fragments xth/xtl; sq[b][n].
// Block (0,0) additionally packs W' = [W1-W2 ; W2] (256x64) into bf16 hi/lo
// A-fragments Wh/Wl for k_pq.
__global__ __launch_bounds__(256) void k_prep(const float* __restrict__ x,
                                              const float* __restrict__ W,
                                              unsigned short* __restrict__ xth,
                                              unsigned short* __restrict__ xtl,
                                              float* __restrict__ xt32,
                                              float* __restrict__ sq,
                                              unsigned short* __restrict__ Wh,
                                              unsigned short* __restrict__ Wl) {
  __shared__ float ts[FIN][65];
  int nt = blockIdx.x, b = blockIdx.y;
  int nbase = nt * 64, tid = threadIdx.x;
  if (nt == 0 && b == 0) {
    for (int u = tid; u < 32 * 512; u += 256) {
      int ot2 = u >> 9, lane = (u >> 3) & 63, e = u & 7;
      int o = (ot2 >> 1) * 16 + (lane & 15);
      int f = (ot2 & 1) * 32 + (lane >> 4) * 8 + e;
      float v = (o < FOUT) ? (W[o * 2 * FIN + f] - W[o * 2 * FIN + FIN + f])
                           : W[(o - FOUT) * 2 * FIN + FIN + f];
      unsigned short h = f2bf(v);
      Wh[u] = h;
      Wl[u] = f2bf(v - bf2f(h));
    }
  }
  for (int i = tid; i < 64 * 64; i += 256) {
    int f = i >> 6, j = i & 63;
    ts[f][j] = x[((size_t)b * FIN + f) * NN + nbase + j];
  }
  __syncthreads();
  if (tid < 64) {
    float s = 0.f;
#pragma unroll
    for (int f = 0; f < FIN; ++f) { float v = ts[f][tid]; s += v * v; }
    sq[b * NN + nbase + tid] = s;
  }
  for (int u = tid; u < 512; u += 256) {
    int lane = u & 63, ck = (u >> 6) & 1, pg = u >> 7;
    int j = pg * 16 + (lane & 15);
    int kg = lane >> 4;
    int fbase = ck * 32 + kg * 8;
    float v[8]; unsigned short h[8], l[8];
#pragma unroll
    for (int e = 0; e < 8; ++e) {
      v[e] = ts[fbase + e][j];
      h[e] = f2bf(v[e]);
      l[e] = f2bf(v[e] - bf2f(h[e]));
    }
    size_t po = (((size_t)b * (NN / 16) + (nbase >> 4) + pg) * 2 + ck) * 512 + lane * 8;
    ushort4* dh = (ushort4*)(xth + po);
    dh[0] = make_ushort4(h[0], h[1], h[2], h[3]);
    dh[1] = make_ushort4(h[4], h[5], h[6], h[7]);
    ushort4* dl = (ushort4*)(xtl + po);
    dl[0] = make_ushort4(l[0], l[1], l[2], l[3]);
    dl[1] = make_ushort4(l[4], l[5], l[6], l[7]);
    float* d32 = xt32 + ((size_t)b * NN + nbase + j) * FIN + fbase;
    *(float4*)d32       = make_float4(v[0], v[1], v[2], v[3]);
    *(float4*)(d32 + 4) = make_float4(v[4], v[5], v[6], v[7]);
  }
}

// ---------------------------------------------------------------- P/Q GEMM (MFMA)
__global__ __launch_bounds__(256) void k_pq(const unsigned short* __restrict__ xth,
                                            const unsigned short* __restrict__ xtl,
                                            const unsigned short* __restrict__ Wh,
                                            const unsigned short* __restrict__ Wl,
                                            const float* __restrict__ bias,
                                            float* __restrict__ Pt,
                                            float* __restrict__ Qt) {
  int L = blockIdx.x;                    // 512 blocks
  int b = (L & 7) | ((L >> 8) << 3);
  int nt64 = (L >> 3) & 31;
  int tid = threadIdx.x, lane = tid & 63, w = tid >> 6;
  bf16x8 aH[4][2], aL[4][2];
#pragma unroll
  for (int t = 0; t < 4; ++t) {
    int ot = w * 4 + t;
#pragma unroll
    for (int ck = 0; ck < 2; ++ck) {
      aH[t][ck] = *(const bf16x8*)(Wh + ((ot * 2 + ck) << 9) + lane * 8);
      aL[t][ck] = *(const bf16x8*)(Wl + ((ot * 2 + ck) << 9) + lane * 8);
    }
  }
  bool isP = (w < 2);
  int orow = (lane >> 4) * 4;
  float4 b4[4];
#pragma unroll
  for (int t = 0; t < 4; ++t) {
    int o = (w * 4 + t) * 16 + orow;
    b4[t] = isP ? *(const float4*)&bias[o] : make_float4(0.f, 0.f, 0.f, 0.f);
  }
  const unsigned short* xhB = xth + (size_t)b * (NN / 16) * 1024;
  const unsigned short* xlB = xtl + (size_t)b * (NN / 16) * 1024;
  float* dstB = (isP ? Pt : Qt) + (size_t)b * NN * FOUT;
#pragma unroll
  for (int nt = 0; nt < 4; ++nt) {
    int p = nt64 * 4 + nt;
    size_t pb = (size_t)p * 1024 + lane * 8;
    bf16x8 bh0 = *(const bf16x8*)(xhB + pb);
    bf16x8 bh1 = *(const bf16x8*)(xhB + pb + 512);
    bf16x8 bl0 = *(const bf16x8*)(xlB + pb);
    bf16x8 bl1 = *(const bf16x8*)(xlB + pb + 512);
    int n = p * 16 + (lane & 15);
#pragma unroll
    for (int t = 0; t < 4; ++t) {
      f32x4 acc = {0.f, 0.f, 0.f, 0.f};
      acc = __builtin_amdgcn_mfma_f32_16x16x32_bf16(aH[t][0], bh0, acc, 0, 0, 0);
      acc = __builtin_amdgcn_mfma_f32_16x16x32_bf16(aH[t][1], bh1, acc, 0, 0, 0);
      acc = __builtin_amdgcn_mfma_f32_16x16x32_bf16(aH[t][0], bl0, acc, 0, 0, 0);
      acc = __builtin_amdgcn_mfma_f32_16x16x32_bf16(aH[t][1], bl1, acc, 0, 0, 0);
      acc = __builtin_amdgcn_mfma_f32_16x16x32_bf16(aL[t][0], bh0, acc, 0, 0, 0);
      acc = __builtin_amdgcn_mfma_f32_16x16x32_bf16(aL[t][1], bh1, acc, 0, 0, 0);
      int o = ((w * 4 + t) * 16 + orow) & 127;
      *(float4*)&dstB[(size_t)n * FOUT + o] =
          make_float4(acc[0] + b4[t].x, acc[1] + b4[t].y,
                      acc[2] + b4[t].z, acc[3] + b4[t].w);
    }
  }
}

// ---------------------------------------------------------------- kNN
__global__ __launch_bounds__(512, 8) void k_knn(const unsigned short* __restrict__ xth,
                                                const unsigned short* __restrict__ xtl,
                                                const float* __restrict__ xt32,
                                                const float* __restrict__ sq,
                                                int* __restrict__ knn) {
  __shared__ unsigned short BjH[4096];   // 8 KB
  __shared__ unsigned short BjL[4096];   // 8 KB
  __shared__ unsigned dtk[32][67];       // 8.4 KB packed keys
  __shared__ unsigned buf[32 * BUFD];    // 14 KB candidate buffers
  __shared__ float sqi_s[32], sqj_s[64];
  __shared__ unsigned flg[2];

  int L = blockIdx.x;
  int b = (L & 7) | ((L >> 9) << 3);     // XCD-local b
  int it = (L >> 3) & 63;
  int ibase = it * 32, tid = threadIdx.x;
  int lane = tid & 63, w = tid >> 6;     // 8 waves
  int tr = w >> 2, tc = w & 3;           // MFMA tile (2x4)

  const unsigned short* xhB = xth + (size_t)b * (NN / 16) * 1024;
  const unsigned short* xlB = xtl + (size_t)b * (NN / 16) * 1024;

  size_t pa = ((size_t)(ibase >> 4) + tr) * 1024;
  bf16x8 ah0 = *(const bf16x8*)(xhB + pa +       lane * 8);
  bf16x8 ah1 = *(const bf16x8*)(xhB + pa + 512 + lane * 8);
  bf16x8 al0 = *(const bf16x8*)(xlB + pa +       lane * 8);
  bf16x8 al1 = *(const bf16x8*)(xlB + pa + 512 + lane * 8);

  if (tid < 32) sqi_s[tid] = sq[b * NN + ibase + tid];
  if (tid < 2) flg[tid] = 0;

  unsigned lst[4], thr[4]; int cnt[4];
#pragma unroll
  for (int r = 0; r < 4; ++r) { lst[r] = 0xFFFFFFFFu; thr[r] = 0xFFFFFFFFu; cnt[r] = 0; }

  gll16(xhB + tid * 8, BjH + tid * 8);
  gll16(xlB + tid * 8, BjL + tid * 8);
  if (tid < 64) sqj_s[tid] = sq[b * NN + tid];

  for (int jt = 0; jt < NN / 64; ++jt) {
    __syncthreads();                     // bar1: staged tile + sqj ready
    if (tid == 0) flg[(jt & 1) ^ 1] = 0; // clear slot read last tile
    {
      int jbase = jt * 64;
      bf16x8 bh0 = *(const bf16x8*)(BjH + (tc * 2 + 0) * 512 + lane * 8);
      bf16x8 bh1 = *(const bf16x8*)(BjH + (tc * 2 + 1) * 512 + lane * 8);
      bf16x8 bl0 = *(const bf16x8*)(BjL + (tc * 2 + 0) * 512 + lane * 8);
      bf16x8 bl1 = *(const bf16x8*)(BjL + (tc * 2 + 1) * 512 + lane * 8);
      f32x4 acc = {0.f, 0.f, 0.f, 0.f};
      acc = __builtin_amdgcn_mfma_f32_16x16x32_bf16(ah0, bh0, acc, 0, 0, 0);
      acc = __builtin_amdgcn_mfma_f32_16x16x32_bf16(ah1, bh1, acc, 0, 0, 0);
      acc = __builtin_amdgcn_mfma_f32_16x16x32_bf16(ah0, bl0, acc, 0, 0, 0);
      acc = __builtin_amdgcn_mfma_f32_16x16x32_bf16(ah1, bl1, acc, 0, 0, 0);
      acc = __builtin_amdgcn_mfma_f32_16x16x32_bf16(al0, bh0, acc, 0, 0, 0);
      acc = __builtin_amdgcn_mfma_f32_16x16x32_bf16(al1, bh1, acc, 0, 0, 0);
      int jl = tc * 16 + (lane & 15);
      int jglob = jbase + jl;
      float sj = sqj_s[jl];
#pragma unroll
      for (int e = 0; e < 4; ++e) {
        int il = tr * 16 + (lane >> 4) * 4 + e;
        float d = fmaxf(sqi_s[il] + sj - 2.f * acc[e], 0.f);
        unsigned key = (__float_as_uint(d) & 0xFFFFF800u) | (unsigned)jglob;
        if (jglob == ibase + il) key = 0xFFFFFFFFu;   // exclude self
        dtk[il][jl] = key;
      }
    }
    __syncthreads();                     // bar2: keys ready, Bj free
    int doflush = flg[jt & 1];           // set during previous tile
    if (jt + 1 < NN / 64) {              // prefetch next tile under selection
      const unsigned short* sh = xhB + (size_t)(jt + 1) * 4096;
      const unsigned short* sl = xlB + (size_t)(jt + 1) * 4096;
      gll16(sh + tid * 8, BjH + tid * 8);
      gll16(sl + tid * 8, BjL + tid * 8);
      if (tid < 64) sqj_s[tid] = sq[b * NN + (jt + 1) * 64 + tid];
    }
    // ---- block-uniform flush FIRST (empties buf, freshens thr)
    if (doflush)
      flush4(lst, cnt, thr, &buf[w * 4 * BUFD], lane);
    // ---- compact survivors (1 ballot + scatter per row)
    u64 below = (1ull << lane) - 1;
#pragma unroll
    for (int r = 0; r < 4; ++r) {
      unsigned key = dtk[w * 4 + r][lane];
      u64 m = __ballot(key < thr[r]);
      if (m) {
        if (key < thr[r]) buf[(w * 4 + r) * BUFD + cnt[r] + __popcll(m & below)] = key;
        cnt[r] += (int)__popcll(m);
      }
    }
    bool trip = cnt[0] > TRIP || cnt[1] > TRIP || cnt[2] > TRIP || cnt[3] > TRIP;
    if (trip && lane == 0) flg[(jt & 1) ^ 1] = 1;
  }
  // final flush
  flush4(lst, cnt, thr, &buf[w * 4 * BUFD], lane);

  // ---- exact fp64 refine: 4 rows' distances + one interleaved 32-wide sort
  const float* x32B = xt32 + (size_t)b * NN * FIN;
  double dd[4]; int jj[4];
#pragma unroll
  for (int r = 0; r < 4; ++r) {
    int iglob = ibase + w * 4 + r;
    int j = (int)(lst[r] & 0x7FFu);
    jj[r] = j;
    if (lane < LCAP) {
      const float4* xi4 = (const float4*)(x32B + (size_t)iglob * FIN);
      const float4* xj4 = (const float4*)(x32B + (size_t)j * FIN);
      double s0 = 0.0, s1 = 0.0;
#pragma unroll
      for (int q = 0; q < 16; q += 2) {
        float4 a0 = xi4[q], c0 = xj4[q];
        float4 a1 = xi4[q + 1], c1 = xj4[q + 1];
        double e0 = (double)a0.x - (double)c0.x;
        double e1 = (double)a0.y - (double)c0.y;
        double e2 = (double)a0.z - (double)c0.z;
        double e3 = (double)a0.w - (double)c0.w;
        double f0 = (double)a1.x - (double)c1.x;
        double f1 = (double)a1.y - (double)c1.y;
        double f2 = (double)a1.z - (double)c1.z;
        double f3 = (double)a1.w - (double)c1.w;
        s0 += e0 * e0 + e1 * e1 + e2 * e2 + e3 * e3;
        s1 += f0 * f0 + f1 * f1 + f2 * f2 + f3 * f3;
      }
      dd[r] = s0 + s1;
    } else {
      dd[r] = 1e300;
    }
  }
  // interleaved bitonic sort over lanes 0..31 (15 stages; strides stay in-half)
#pragma unroll
  for (int size = 2; size <= 32; size <<= 1) {
#pragma unroll
    for (int stride = size >> 1; stride; stride >>= 1) {
      bool dir = (((lane & size) == 0) == ((lane & stride) == 0));
#pragma unroll
      for (int r = 0; r < 4; ++r) {
        double od = __shfl_xor(dd[r], stride);
        int    oj = __shfl_xor(jj[r], stride);
        bool lt = (od < dd[r]) || (od == dd[r] && ((unsigned)oj < (unsigned)jj[r]));
        bool take = dir ? lt : !lt;
        if (take) { dd[r] = od; jj[r] = oj; }
      }
    }
  }
  if (lane < KK) {
#pragma unroll
    for (int r = 0; r < 4; ++r)
      knn[((size_t)b * NN + ibase + w * 4 + r) * KK + lane] = jj[r];
  }
}

// ---------------------------------------------------------------- stats
__global__ __launch_bounds__(512) void k_stats(const float* __restrict__ Pt,
                                               const float* __restrict__ Qt,
                                               const int* __restrict__ knn,
                                               float* __restrict__ mxT,
                                               float* __restrict__ mnT,
                                               double* __restrict__ sums) {
  __shared__ int ks[64 * KK];           // 5 KB
  __shared__ float rs[2][4][FOUT];      // 4 KB
  int L = blockIdx.x;                   // 512 blocks
  int b = (L & 7) | ((L >> 8) << 3);
  int nt = (L >> 3) & 31;
  int tid = threadIdx.x;
  int o = tid & 127, ng = tid >> 7;
  int nbase = nt * 64;
  for (int i = tid; i < 64 * KK; i += 512)
    ks[i] = knn[((size_t)b * NN + nbase) * KK + i];
  __syncthreads();
  const float* PtB = Pt + (size_t)b * NN * FOUT + o;
  const float* QtB = Qt + (size_t)b * NN * FOUT + o;
  float s1 = 0.f, s2 = 0.f;
  for (int nl = ng * 16; nl < ng * 16 + 16; ++nl) {
    int n = nbase + nl;
    float p = PtB[(size_t)n * FOUT];
    float vmx = -3.4e38f, vmn = 3.4e38f;
#pragma unroll
    for (int k = 0; k < KK; ++k) {
      float q = QtB[(size_t)ks[nl * KK + k] * FOUT];
      float y = p + q;
      s1 += y; s2 = fmaf(y, y, s2);
      vmx = fmaxf(vmx, y); vmn = fminf(vmn, y);
    }
    mxT[((size_t)b * NN + n) * FOUT + o] = vmx;
    mnT[((size_t)b * NN + n) * FOUT + o] = vmn;
  }
  rs[0][ng][o] = s1; rs[1][ng][o] = s2;
  __syncthreads();
  if (tid < FOUT) {
    float a = rs[0][0][tid] + rs[0][1][tid] + rs[0][2][tid] + rs[0][3][tid];
    float c = rs[1][0][tid] + rs[1][1][tid] + rs[1][2][tid] + rs[1][3][tid];
    atomicAdd(&sums[tid], (double)a);
    atomicAdd(&sums[FOUT + tid], (double)c);
  }
}

// ---------------------------------------------------------------- epilogue (finalize fused)
__global__ __launch_bounds__(256) void k_out(const float* __restrict__ mxT,
                                             const float* __restrict__ mnT,
                                             const double* __restrict__ sums,
                                             const float* __restrict__ gamma,
                                             const float* __restrict__ beta,
                                             float* __restrict__ out) {
  __shared__ float ssl[2][FOUT];
  __shared__ float ts[64][65];
  int tid = threadIdx.x;
  if (tid < FOUT) {
    double cnt = (double)Bb * NN * KK;
    double mean = sums[tid] / cnt;
    double var = sums[FOUT + tid] / cnt - mean * mean;
    double inv = 1.0 / sqrt(var + 1e-5);
    double scale = (double)gamma[tid] * inv;
    ssl[0][tid] = (float)scale;
    ssl[1][tid] = (float)((double)beta[tid] - mean * scale);
  }
  __syncthreads();
  int L = blockIdx.x;
  int b = (L & 7) | ((L >> 9) << 3);
  int nt = (L >> 3) & 31, ot = (L >> 8) & 1;
  int nbase = nt * 64, obase = ot * 64;
  for (int i = tid; i < 4096; i += 256) {
    int o_l = i & 63, n_l = i >> 6;
    int o = obase + o_l;
    const float* src = (ssl[0][o] >= 0.f) ? mxT : mnT;
    ts[o_l][n_l] = src[((size_t)b * NN + nbase + n_l) * FOUT + o];
  }
  __syncthreads();
  for (int i = tid; i < 4096; i += 256) {
    int n_l = i & 63, o_l = i >> 6;
    int o = obase + o_l;
    out[((size_t)b * FOUT + o) * NN + nbase + n_l] =
        fmaxf(fmaf(ssl[0][o], ts[o_l][n_l], ssl[1][o]), 0.f);
  }
}

// ---------------------------------------------------------------- launch
extern "C" void kernel_launch(void* const* d_in, const int* in_sizes, int n_in,
                              void* d_out, int out_size, void* d_ws, size_t ws_size,
                              hipStream_t stream) {
  const float* x     = (const float*)d_in[0];
  const float* W     = (const float*)d_in[1];
  const float* bias  = (const float*)d_in[2];
  const float* gamma = (const float*)d_in[3];
  const float* beta  = (const float*)d_in[4];
  float* out = (float*)d_out;

  char* ws = (char*)d_ws;
  const size_t PN = (size_t)Bb * FOUT * NN;          // 4,194,304
  float* Pt = (float*)ws;  ws += PN * 4;
  float* Qt = (float*)ws;  ws += PN * 4;
  float* mxT = (float*)ws; ws += PN * 4;             // 16 MB, aliased with xt*
  float* mnT = (float*)ws; ws += PN * 4;
  float* sq = (float*)ws;  ws += (size_t)Bb * NN * 4;
  int*   knn = (int*)ws;   ws += (size_t)Bb * NN * KK * 4;
  double* sums = (double*)ws; ws += 2 * FOUT * 8;
  unsigned short* Wh = (unsigned short*)ws; ws += 32 * 512 * 2;
  unsigned short* Wl = (unsigned short*)ws; ws += 32 * 512 * 2;

  // xth/xtl/xt32 alias mxT (4+4+8 MB); k_stats overwrites mxT only after
  // k_knn finished reading them (stream-ordered).
  unsigned short* xth = (unsigned short*)mxT;
  unsigned short* xtl = xth + (size_t)Bb * NN * FIN;
  float* xt32 = (float*)(xtl + (size_t)Bb * NN * FIN);

  hipMemsetAsync(sums, 0, 2 * FOUT * 8, stream);

  k_prep<<<dim3(NN / 64, Bb), 256, 0, stream>>>(x, W, xth, xtl, xt32, sq, Wh, Wl);
  k_pq<<<512, 256, 0, stream>>>(xth, xtl, Wh, Wl, bias, Pt, Qt);
  k_knn<<<1024, 512, 0, stream>>>(xth, xtl, xt32, sq, knn);
  k_stats<<<512, 512, 0, stream>>>(Pt, Qt, knn, mxT, mnT, sums);
  k_out<<<1024, 256, 0, stream>>>(mxT, mnT, sums, gamma, beta, out);
}